// Round 3
// baseline (518.363 us; speedup 1.0000x reference)
//
#include <hip/hip_runtime.h>
#include <hip/hip_bf16.h>
#include <math.h>

typedef short bf16x8 __attribute__((ext_vector_type(8)));
typedef float f32x4 __attribute__((ext_vector_type(4)));

__device__ __forceinline__ unsigned short f2bfu(float f) {
    __hip_bfloat16 h = __float2bfloat16(f);
    return __builtin_bit_cast(unsigned short, h);
}

__device__ __forceinline__ void gload_lds16(const void* gsrc, void* ldst) {
    __builtin_amdgcn_global_load_lds((const __attribute__((address_space(1))) void*)gsrc,
                                     (__attribute__((address_space(3))) void*)ldst,
                                     16, 0, 0);
}

// ---------------- f32 -> bf16 convert ----------------
__global__ __launch_bounds__(256)
void cvt_bf16_kernel(const float4* __restrict__ in, ushort4* __restrict__ out, int n4) {
    int i = blockIdx.x * 256 + threadIdx.x;
    if (i >= n4) return;
    float4 v = in[i];
    ushort4 o;
    o.x = f2bfu(v.x); o.y = f2bfu(v.y); o.z = f2bfu(v.z); o.w = f2bfu(v.w);
    out[i] = o;
}

// ---------------- BT GEMM: C[M,N] = A[M,K] * W[N,K]^T + bias, epilogues ----------------
enum { EPI_BF16 = 0, EPI_QSCALE = 1, EPI_RESF32 = 2, EPI_GELU = 3, EPI_VT = 4 };

template<int EPI>
__global__ __launch_bounds__(256, 2)
void gemm_bt(const __hip_bfloat16* __restrict__ A,
             const __hip_bfloat16* __restrict__ W,
             const float* __restrict__ bias,
             const float* __restrict__ res,
             float scale,
             void* __restrict__ outp,
             int M, int N, int K)
{
    __shared__ __hip_bfloat16 As[128 * 32];
    __shared__ __hip_bfloat16 Ws[128 * 32];
    const int tid = threadIdx.x;
    const int lane = tid & 63;
    const int wid = tid >> 6;
    const int wr = wid >> 1, wc = wid & 1;
    const int g = lane >> 4, lr = lane & 15;

    // XCD-aware bijective swizzle (T1/m204): XCD x gets contiguous tile chunk
    // -> consecutive tiles in a chunk share the same W column panel (L2 reuse).
    const int gx = gridDim.x;
    const int nwg = gx * gridDim.y;
    const int orig = blockIdx.y * gx + blockIdx.x;
    const int chunk = nwg >> 3;
    const int nl = (orig & 7) * chunk + (orig >> 3);
    const int bx = nl % gx;
    const int by = nl / gx;
    const int row0 = bx * 128;
    const int col0 = by * 128;

    f32x4 acc[4][4];
    const f32x4 zero = {0.f, 0.f, 0.f, 0.f};
#pragma unroll
    for (int m = 0; m < 4; ++m)
#pragma unroll
        for (int n = 0; n < 4; ++n) acc[m][n] = zero;

    const int c0 = tid, c1 = tid + 256;
    const int ar0 = c0 >> 2, ac0 = (c0 & 3) * 8;
    const int ar1 = c1 >> 2, ac1 = (c1 & 3) * 8;

    for (int k0 = 0; k0 < K; k0 += 32) {
        gload_lds16(A + (size_t)(row0 + ar0) * K + k0 + ac0, (char*)As + c0 * 16);
        gload_lds16(A + (size_t)(row0 + ar1) * K + k0 + ac1, (char*)As + c1 * 16);
        gload_lds16(W + (size_t)(col0 + ar0) * K + k0 + ac0, (char*)Ws + c0 * 16);
        gload_lds16(W + (size_t)(col0 + ar1) * K + k0 + ac1, (char*)Ws + c1 * 16);
        __syncthreads();
        bf16x8 af[4], wf[4];
#pragma unroll
        for (int m = 0; m < 4; ++m)
            af[m] = *(const bf16x8*)(As + (wr * 64 + m * 16 + lr) * 32 + g * 8);
#pragma unroll
        for (int n = 0; n < 4; ++n)
            wf[n] = *(const bf16x8*)(Ws + (wc * 64 + n * 16 + lr) * 32 + g * 8);
#pragma unroll
        for (int m = 0; m < 4; ++m)
#pragma unroll
            for (int n = 0; n < 4; ++n)
                acc[m][n] = __builtin_amdgcn_mfma_f32_16x16x32_bf16(af[m], wf[n], acc[m][n], 0, 0, 0);
        __syncthreads();
    }

#pragma unroll
    for (int n = 0; n < 4; ++n) {
        const int cc = col0 + wc * 64 + n * 16 + lr;
        const float bv = bias[cc];
#pragma unroll
        for (int m = 0; m < 4; ++m) {
            const int rbase = row0 + wr * 64 + m * 16 + g * 4;
            if (EPI == EPI_VT) {
                // write V transposed: [b][h][dh][s], pack 4 consecutive tokens
                ushort4 u;
                u.x = f2bfu(acc[m][n][0] + bv);
                u.y = f2bfu(acc[m][n][1] + bv);
                u.z = f2bfu(acc[m][n][2] + bv);
                u.w = f2bfu(acc[m][n][3] + bv);
                const int h_ = cc >> 6, dh = cc & 63;
                const int bb = rbase >> 11;
                const int s = rbase & 2047;
                *(ushort4*)((__hip_bfloat16*)outp +
                            (((size_t)bb * 16 + h_) * 64 + dh) * 2048 + s) = u;
            } else {
#pragma unroll
                for (int r = 0; r < 4; ++r) {
                    const size_t idx = (size_t)(rbase + r) * N + cc;
                    float v = acc[m][n][r] + bv;
                    if (EPI == EPI_QSCALE) {
                        ((__hip_bfloat16*)outp)[idx] = __float2bfloat16(v * scale);
                    } else if (EPI == EPI_BF16) {
                        ((__hip_bfloat16*)outp)[idx] = __float2bfloat16(v);
                    } else if (EPI == EPI_RESF32) {
                        ((float*)outp)[idx] = v + res[idx];
                    } else if (EPI == EPI_GELU) {
                        float gv = 0.5f * v * (1.0f + erff(v * 0.70710678118654752f));
                        ((__hip_bfloat16*)outp)[idx] = __float2bfloat16(gv);
                    }
                }
            }
        }
    }
}

// ---------------- Flash attention v2.1 ----------------
// grid: (S/256, B*H); block 256 (4 waves); wave owns 64 q rows; KV tile = 64.
// Swapped QK^T, defer-max, double-buffered K/V via global_load_lds, all LDS
// tiles 128B-stride + XOR-16B-block swizzle (conflict-free per 8-lane phase).
__global__ __launch_bounds__(256, 2)
void attn_flash2(const __hip_bfloat16* __restrict__ Q,
                 const __hip_bfloat16* __restrict__ K,
                 const __hip_bfloat16* __restrict__ VT,   // [b][h][dh][s]
                 const unsigned char* __restrict__ kpm,
                 __hip_bfloat16* __restrict__ O)
{
    __shared__ __hip_bfloat16 Ks[2][64 * 64];
    __shared__ __hip_bfloat16 VTs[2][64 * 64];
    __shared__ __hip_bfloat16 Plds[4][64 * 64];

    const int tid = threadIdx.x;
    const int lane = tid & 63;
    const int w = tid >> 6;
    const int g = lane >> 4, lr = lane & 15;

    // XCD swizzle: each XCD owns 8 consecutive heads (all their q-blocks) -> K/V L2 reuse
    const int orig = blockIdx.y * 8 + blockIdx.x;
    const int nl = (orig & 7) * 64 + (orig >> 3);
    const int qb = nl & 7;
    const int bh = nl >> 3;

    const int b = bh >> 4, h = bh & 15;
    const int q0 = qb * 256 + w * 64;
    const size_t tokbase = (size_t)b * 2048;
    const __hip_bfloat16* VTbh = VT + (size_t)bh * 64 * 2048;

    // Q fragments: B-operand of swapped QK^T: Q[q=qn*16+lr][d=f*32+g*8+j]
    bf16x8 qf[4][2];
#pragma unroll
    for (int qn = 0; qn < 4; ++qn)
#pragma unroll
        for (int f = 0; f < 2; ++f)
            qf[qn][f] = *(const bf16x8*)(Q + (tokbase + q0 + qn * 16 + lr) * 1024 +
                                         h * 64 + f * 32 + g * 8);

    f32x4 o[4][4];   // [qa][nd]: O[q=qa*16+g*4+r][d=nd*16+lr]
    const f32x4 zero = {0.f, 0.f, 0.f, 0.f};
#pragma unroll
    for (int qa = 0; qa < 4; ++qa)
#pragma unroll
        for (int nd = 0; nd < 4; ++nd) o[qa][nd] = zero;
    float m_run[4], l_part[4];   // per-lane stats for q = qn*16+lr
#pragma unroll
    for (int qn = 0; qn < 4; ++qn) { m_run[qn] = -1e30f; l_part[qn] = 0.f; }

    __hip_bfloat16* Pw = Plds[w];
    const int rowl = lane >> 3;       // staging: row within 8-row group
    const int blkp = lane & 7;        // staging: 16B block position in row

    // stage K tile [64 key][64 d] and VT tile [64 d][64 s] (both 128B rows),
    // linear LDS dest, XOR-swizzled global source block.
    auto stage = [&](int bufi, int kv0) {
#pragma unroll
        for (int iss = 0; iss < 2; ++iss) {
            const int row = w * 16 + iss * 8 + rowl;
            const int sblk = blkp ^ (row & 7);
            gload_lds16(K + (tokbase + kv0 + row) * 1024 + h * 64 + sblk * 8,
                        (char*)&Ks[bufi][(w * 16 + iss * 8) * 64] + (lane & 63) * 16);
            gload_lds16(VTbh + (size_t)row * 2048 + kv0 + sblk * 8,
                        (char*)&VTs[bufi][(w * 16 + iss * 8) * 64] + (lane & 63) * 16);
        }
    };

    stage(0, 0);
    __syncthreads();
    int buf = 0;

    for (int t = 0; t < 32; ++t) {
        const int kv0 = t * 64;
        if (t < 31) stage(buf ^ 1, kv0 + 64);

        // ---- S^T = K * Q^T: st[km][qn], lane holds S[key=km*16+g*4+r][q=qn*16+lr]
        f32x4 st[4][4];
#pragma unroll
        for (int km = 0; km < 4; ++km) {
            bf16x8 kf[2];
#pragma unroll
            for (int f = 0; f < 2; ++f)
                kf[f] = *(const bf16x8*)(&Ks[buf][(km * 16 + lr) * 64 +
                                                  (((f * 4 + g) ^ (lr & 7)) * 8)]);
#pragma unroll
            for (int qn = 0; qn < 4; ++qn) {
                st[km][qn] = __builtin_amdgcn_mfma_f32_16x16x32_bf16(kf[0], qf[qn][0], zero, 0, 0, 0);
                st[km][qn] = __builtin_amdgcn_mfma_f32_16x16x32_bf16(kf[1], qf[qn][1], st[km][qn], 0, 0, 0);
            }
        }

        // ---- key padding mask (rare path; all-false in this workload)
#pragma unroll
        for (int km = 0; km < 4; ++km) {
            const unsigned mu = *(const unsigned*)(kpm + tokbase + kv0 + km * 16 + g * 4);
            if (__any((int)(mu != 0u))) {
                const float NEG = -1e30f;
#pragma unroll
                for (int r = 0; r < 4; ++r) {
                    if ((mu >> (8 * r)) & 0xFFu) {
#pragma unroll
                        for (int qn = 0; qn < 4; ++qn) st[km][qn][r] = NEG;
                    }
                }
            }
        }

        // ---- defer-max online softmax
        float pm[4];
#pragma unroll
        for (int qn = 0; qn < 4; ++qn) {
            float a0 = fmaxf(fmaxf(st[0][qn][0], st[0][qn][1]), fmaxf(st[0][qn][2], st[0][qn][3]));
            float a1 = fmaxf(fmaxf(st[1][qn][0], st[1][qn][1]), fmaxf(st[1][qn][2], st[1][qn][3]));
            float a2 = fmaxf(fmaxf(st[2][qn][0], st[2][qn][1]), fmaxf(st[2][qn][2], st[2][qn][3]));
            float a3 = fmaxf(fmaxf(st[3][qn][0], st[3][qn][1]), fmaxf(st[3][qn][2], st[3][qn][3]));
            pm[qn] = fmaxf(fmaxf(a0, a1), fmaxf(a2, a3));
        }
        const int trig = (pm[0] > m_run[0] + 8.f) | (pm[1] > m_run[1] + 8.f) |
                         (pm[2] > m_run[2] + 8.f) | (pm[3] > m_run[3] + 8.f);
        if (__any(trig)) {
            float alpha_q[4];
#pragma unroll
            for (int qn = 0; qn < 4; ++qn) {
                float rm = pm[qn];
                rm = fmaxf(rm, __shfl_xor(rm, 16));
                rm = fmaxf(rm, __shfl_xor(rm, 32));
                const float mnew = fmaxf(m_run[qn], rm);
                const float al = __expf(m_run[qn] - mnew);
                l_part[qn] *= al;
                m_run[qn] = mnew;
                alpha_q[qn] = al;
            }
#pragma unroll
            for (int qa = 0; qa < 4; ++qa)
#pragma unroll
                for (int r = 0; r < 4; ++r) {
                    const float av = __shfl(alpha_q[qa], g * 4 + r, 16);
#pragma unroll
                    for (int nd = 0; nd < 4; ++nd) o[qa][nd][r] *= av;
                }
        }

        // ---- P = exp(S - m), accumulate l, pack to bf16, b64 store to Plds[q][k]
        // LDS row q (128B), chunk (km*2+(g>>1)) XOR-swizzled by (lr&7), +8B for odd g.
#pragma unroll
        for (int qn = 0; qn < 4; ++qn) {
            const float mm = m_run[qn];
#pragma unroll
            for (int km = 0; km < 4; ++km) {
                const float p0 = __expf(st[km][qn][0] - mm);
                const float p1 = __expf(st[km][qn][1] - mm);
                const float p2 = __expf(st[km][qn][2] - mm);
                const float p3 = __expf(st[km][qn][3] - mm);
                l_part[qn] += (p0 + p1) + (p2 + p3);
                uint2 pk;
                pk.x = (unsigned)f2bfu(p0) | ((unsigned)f2bfu(p1) << 16);
                pk.y = (unsigned)f2bfu(p2) | ((unsigned)f2bfu(p3) << 16);
                const int cs = (km * 2 + (g >> 1)) ^ (lr & 7);
                *(uint2*)(Pw + (qn * 16 + lr) * 64 + cs * 8 + (g & 1) * 4) = pk;
            }
        }

        // ---- O += P * V
#pragma unroll
        for (int f = 0; f < 2; ++f) {
            bf16x8 pa[4];
#pragma unroll
            for (int qa = 0; qa < 4; ++qa)
                pa[qa] = *(const bf16x8*)(Pw + (qa * 16 + lr) * 64 +
                                          (((f * 4 + g) ^ (lr & 7)) * 8));
#pragma unroll
            for (int nd = 0; nd < 4; ++nd) {
                bf16x8 vb = *(const bf16x8*)(&VTs[buf][(nd * 16 + lr) * 64 +
                                                       (((f * 4 + g) ^ (lr & 7)) * 8)]);
#pragma unroll
                for (int qa = 0; qa < 4; ++qa)
                    o[qa][nd] = __builtin_amdgcn_mfma_f32_16x16x32_bf16(pa[qa], vb, o[qa][nd], 0, 0, 0);
            }
        }

        __syncthreads();
        buf ^= 1;
    }

    // ---- epilogue: 1/l scaling + store
    float linv[4];
#pragma unroll
    for (int qn = 0; qn < 4; ++qn) {
        float lt = l_part[qn];
        lt += __shfl_xor(lt, 16);
        lt += __shfl_xor(lt, 32);
        linv[qn] = 1.0f / lt;
    }
#pragma unroll
    for (int qa = 0; qa < 4; ++qa)
#pragma unroll
        for (int r = 0; r < 4; ++r) {
            const float lv = __shfl(linv[qa], g * 4 + r, 16);
            const size_t row = tokbase + q0 + qa * 16 + g * 4 + r;
#pragma unroll
            for (int nd = 0; nd < 4; ++nd)
                O[row * 1024 + h * 64 + nd * 16 + lr] = __float2bfloat16(o[qa][nd][r] * lv);
        }
}

// ---------------- LayerNorm (row = 1024 floats) ----------------
__global__ __launch_bounds__(256)
void ln_kernel(const float* __restrict__ in, const float* __restrict__ gamma,
               const float* __restrict__ beta, float* __restrict__ outf,
               __hip_bfloat16* __restrict__ outb)
{
    const int row = blockIdx.x;
    const int tid = threadIdx.x;
    float4 v = ((const float4*)(in + (size_t)row * 1024))[tid];
    float s = v.x + v.y + v.z + v.w;
    float s2 = v.x * v.x + v.y * v.y + v.z * v.z + v.w * v.w;
#pragma unroll
    for (int off = 1; off < 64; off <<= 1) {
        s += __shfl_xor(s, off);
        s2 += __shfl_xor(s2, off);
    }
    __shared__ float red[8];
    const int wv = tid >> 6;
    if ((tid & 63) == 0) { red[wv] = s; red[4 + wv] = s2; }
    __syncthreads();
    s = red[0] + red[1] + red[2] + red[3];
    s2 = red[4] + red[5] + red[6] + red[7];
    const float mean = s * (1.f / 1024.f);
    const float var = s2 * (1.f / 1024.f) - mean * mean;
    const float rstd = rsqrtf(var + 1e-5f);
    float4 gm = ((const float4*)gamma)[tid];
    float4 bt = ((const float4*)beta)[tid];
    float4 y;
    y.x = (v.x - mean) * rstd * gm.x + bt.x;
    y.y = (v.y - mean) * rstd * gm.y + bt.y;
    y.z = (v.z - mean) * rstd * gm.z + bt.z;
    y.w = (v.w - mean) * rstd * gm.w + bt.w;
    ((float4*)(outf + (size_t)row * 1024))[tid] = y;
    if (outb) {
        ushort4 ub;
        ub.x = f2bfu(y.x); ub.y = f2bfu(y.y); ub.z = f2bfu(y.z); ub.w = f2bfu(y.w);
        ((ushort4*)outb)[row * 256 + tid] = ub;
    }
}

// ---------------- host ----------------
extern "C" void kernel_launch(void* const* d_in, const int* in_sizes, int n_in,
                              void* d_out, int out_size, void* d_ws, size_t ws_size,
                              hipStream_t stream)
{
    const float* x    = (const float*)d_in[0];
    const unsigned char* kpm = (const unsigned char*)d_in[1];
    const float* Wq = (const float*)d_in[2];
    const float* bq = (const float*)d_in[3];
    const float* Wk = (const float*)d_in[4];
    const float* bk = (const float*)d_in[5];
    const float* Wv = (const float*)d_in[6];
    const float* bv = (const float*)d_in[7];
    const float* Wo = (const float*)d_in[8];
    const float* bo = (const float*)d_in[9];
    const float* W1 = (const float*)d_in[10];
    const float* b1 = (const float*)d_in[11];
    const float* W2 = (const float*)d_in[12];
    const float* b2 = (const float*)d_in[13];
    const float* ln1g = (const float*)d_in[14];
    const float* ln1b = (const float*)d_in[15];
    const float* ln2g = (const float*)d_in[16];
    const float* ln2b = (const float*)d_in[17];
    float* out = (float*)d_out;

    char* ws = (char*)d_ws;
    const size_t SZ_ND2 = (size_t)8192 * 1024 * 2;   // 16.8 MB
    size_t off = 0;
    __hip_bfloat16* xb  = (__hip_bfloat16*)(ws + off); off += SZ_ND2;
    __hip_bfloat16* wqb = (__hip_bfloat16*)(ws + off); off += (size_t)1024 * 1024 * 2;
    __hip_bfloat16* wkb = (__hip_bfloat16*)(ws + off); off += (size_t)1024 * 1024 * 2;
    __hip_bfloat16* wvb = (__hip_bfloat16*)(ws + off); off += (size_t)1024 * 1024 * 2;
    __hip_bfloat16* wob = (__hip_bfloat16*)(ws + off); off += (size_t)1024 * 1024 * 2;
    __hip_bfloat16* w1b = (__hip_bfloat16*)(ws + off); off += (size_t)4096 * 1024 * 2;
    __hip_bfloat16* w2b = (__hip_bfloat16*)(ws + off); off += (size_t)4096 * 1024 * 2;
    const size_t qkv0 = off;
    __hip_bfloat16* qbp = (__hip_bfloat16*)(ws + off); off += SZ_ND2;
    __hip_bfloat16* kbp = (__hip_bfloat16*)(ws + off); off += SZ_ND2;
    __hip_bfloat16* vtg = (__hip_bfloat16*)(ws + off); off += SZ_ND2;  // [b][h][dh][s]
    __hip_bfloat16* abp = (__hip_bfloat16*)(ws + off); off += SZ_ND2;
    __hip_bfloat16* hbp = (__hip_bfloat16*)(ws + qkv0);  // aliases q/k/vt/a (dead by then)
    float* y1 = (float*)(ws + off); off += (size_t)8192 * 1024 * 4;
    float* x1 = (float*)(ws + off); off += (size_t)8192 * 1024 * 4;
    __hip_bfloat16* x1b = (__hip_bfloat16*)(ws + off); off += SZ_ND2;
    float* y2 = y1;

    auto cvt = [&](const float* src, void* dst, int n) {
        cvt_bf16_kernel<<<n / 1024, 256, 0, stream>>>((const float4*)src, (ushort4*)dst, n / 4);
    };
    cvt(x,  xb,  8192 * 1024);
    cvt(Wq, wqb, 1024 * 1024);
    cvt(Wk, wkb, 1024 * 1024);
    cvt(Wv, wvb, 1024 * 1024);
    cvt(Wo, wob, 1024 * 1024);
    cvt(W1, w1b, 4096 * 1024);
    cvt(W2, w2b, 4096 * 1024);

    dim3 blk(256);
    dim3 gD(64, 8);    // M/128 x 1024/128
    dim3 gF(64, 32);   // M/128 x 4096/128

    gemm_bt<EPI_QSCALE><<<gD, blk, 0, stream>>>(xb, wqb, bq, nullptr, 0.125f, qbp, 8192, 1024, 1024);
    gemm_bt<EPI_BF16>  <<<gD, blk, 0, stream>>>(xb, wkb, bk, nullptr, 1.0f,   kbp, 8192, 1024, 1024);
    gemm_bt<EPI_VT>    <<<gD, blk, 0, stream>>>(xb, wvb, bv, nullptr, 1.0f,   vtg, 8192, 1024, 1024);

    attn_flash2<<<dim3(8, 64), blk, 0, stream>>>(qbp, kbp, vtg, kpm, abp);

    gemm_bt<EPI_RESF32><<<gD, blk, 0, stream>>>(abp, wob, bo, x, 1.0f, y1, 8192, 1024, 1024);
    ln_kernel<<<8192, 256, 0, stream>>>(y1, ln1g, ln1b, x1, x1b);

    gemm_bt<EPI_GELU>  <<<gF, blk, 0, stream>>>(x1b, w1b, b1, nullptr, 1.0f, hbp, 8192, 4096, 1024);
    gemm_bt<EPI_RESF32><<<gD, blk, 0, stream>>>(hbp, w2b, b2, x1, 1.0f, y2, 8192, 1024, 4096);
    ln_kernel<<<8192, 256, 0, stream>>>(y2, ln2g, ln2b, out, nullptr);
}

// Round 4
// 472.704 us; speedup vs baseline: 1.0966x; 1.0966x over previous
//
#include <hip/hip_runtime.h>
#include <hip/hip_bf16.h>
#include <math.h>

typedef short bf16x8 __attribute__((ext_vector_type(8)));
typedef float f32x4 __attribute__((ext_vector_type(4)));

__device__ __forceinline__ unsigned short f2bfu(float f) {
    __hip_bfloat16 h = __float2bfloat16(f);
    return __builtin_bit_cast(unsigned short, h);
}

__device__ __forceinline__ float fexp2(float x) {
    float r;
    asm("v_exp_f32 %0, %1" : "=v"(r) : "v"(x));
    return r;
}

__device__ __forceinline__ unsigned cvtpk_bf16(float lo, float hi) {
    unsigned r;
    asm("v_cvt_pk_bf16_f32 %0, %1, %2" : "=v"(r) : "v"(lo), "v"(hi));
    return r;
}

__device__ __forceinline__ void gload_lds16(const void* gsrc, void* ldst) {
    __builtin_amdgcn_global_load_lds((const __attribute__((address_space(1))) void*)gsrc,
                                     (__attribute__((address_space(3))) void*)ldst,
                                     16, 0, 0);
}

// ---------------- f32 -> bf16 convert ----------------
__global__ __launch_bounds__(256)
void cvt_bf16_kernel(const float4* __restrict__ in, ushort4* __restrict__ out, int n4) {
    int i = blockIdx.x * 256 + threadIdx.x;
    if (i >= n4) return;
    float4 v = in[i];
    ushort4 o;
    o.x = f2bfu(v.x); o.y = f2bfu(v.y); o.z = f2bfu(v.z); o.w = f2bfu(v.w);
    out[i] = o;
}

// ---------------- BT GEMM: C[M,N] = A[M,K] * W[N,K]^T + bias, epilogues ----------------
enum { EPI_BF16 = 0, EPI_QSCALE = 1, EPI_RESF32 = 2, EPI_GELU = 3, EPI_VT = 4 };

template<int EPI>
__global__ __launch_bounds__(256, 2)
void gemm_bt(const __hip_bfloat16* __restrict__ A,
             const __hip_bfloat16* __restrict__ W,
             const float* __restrict__ bias,
             const float* __restrict__ res,
             float scale,
             void* __restrict__ outp,
             int M, int N, int K)
{
    __shared__ __hip_bfloat16 As[128 * 32];
    __shared__ __hip_bfloat16 Ws[128 * 32];
    const int tid = threadIdx.x;
    const int lane = tid & 63;
    const int wid = tid >> 6;
    const int wr = wid >> 1, wc = wid & 1;
    const int g = lane >> 4, lr = lane & 15;
    // default round-robin dispatch is already a good XCD partition for these
    // shapes: XCD x gets row-tiles bx === x (mod 8) -> per-XCD A set 2MB (L2-fit).
    const int row0 = blockIdx.x * 128;
    const int col0 = blockIdx.y * 128;

    f32x4 acc[4][4];
    const f32x4 zero = {0.f, 0.f, 0.f, 0.f};
#pragma unroll
    for (int m = 0; m < 4; ++m)
#pragma unroll
        for (int n = 0; n < 4; ++n) acc[m][n] = zero;

    const int c0 = tid, c1 = tid + 256;
    const int ar0 = c0 >> 2, ac0 = (c0 & 3) * 8;
    const int ar1 = c1 >> 2, ac1 = (c1 & 3) * 8;

    for (int k0 = 0; k0 < K; k0 += 32) {
        gload_lds16(A + (size_t)(row0 + ar0) * K + k0 + ac0, (char*)As + c0 * 16);
        gload_lds16(A + (size_t)(row0 + ar1) * K + k0 + ac1, (char*)As + c1 * 16);
        gload_lds16(W + (size_t)(col0 + ar0) * K + k0 + ac0, (char*)Ws + c0 * 16);
        gload_lds16(W + (size_t)(col0 + ar1) * K + k0 + ac1, (char*)Ws + c1 * 16);
        __syncthreads();
        bf16x8 af[4], wf[4];
#pragma unroll
        for (int m = 0; m < 4; ++m)
            af[m] = *(const bf16x8*)(As + (wr * 64 + m * 16 + lr) * 32 + g * 8);
#pragma unroll
        for (int n = 0; n < 4; ++n)
            wf[n] = *(const bf16x8*)(Ws + (wc * 64 + n * 16 + lr) * 32 + g * 8);
#pragma unroll
        for (int m = 0; m < 4; ++m)
#pragma unroll
            for (int n = 0; n < 4; ++n)
                acc[m][n] = __builtin_amdgcn_mfma_f32_16x16x32_bf16(af[m], wf[n], acc[m][n], 0, 0, 0);
        __syncthreads();
    }

#pragma unroll
    for (int n = 0; n < 4; ++n) {
        const int cc = col0 + wc * 64 + n * 16 + lr;
        const float bv = bias[cc];
#pragma unroll
        for (int m = 0; m < 4; ++m) {
            const int rbase = row0 + wr * 64 + m * 16 + g * 4;
            if (EPI == EPI_VT) {
                // write V transposed: [b][h][dh][s], pack 4 consecutive tokens
                ushort4 u;
                u.x = f2bfu(acc[m][n][0] + bv);
                u.y = f2bfu(acc[m][n][1] + bv);
                u.z = f2bfu(acc[m][n][2] + bv);
                u.w = f2bfu(acc[m][n][3] + bv);
                const int h_ = cc >> 6, dh = cc & 63;
                const int bb = rbase >> 11;
                const int s = rbase & 2047;
                *(ushort4*)((__hip_bfloat16*)outp +
                            (((size_t)bb * 16 + h_) * 64 + dh) * 2048 + s) = u;
            } else {
#pragma unroll
                for (int r = 0; r < 4; ++r) {
                    const size_t idx = (size_t)(rbase + r) * N + cc;
                    float v = acc[m][n][r] + bv;
                    if (EPI == EPI_QSCALE) {
                        ((__hip_bfloat16*)outp)[idx] = __float2bfloat16(v * scale);
                    } else if (EPI == EPI_BF16) {
                        ((__hip_bfloat16*)outp)[idx] = __float2bfloat16(v);
                    } else if (EPI == EPI_RESF32) {
                        ((float*)outp)[idx] = v + res[idx];
                    } else if (EPI == EPI_GELU) {
                        float gv = 0.5f * v * (1.0f + erff(v * 0.70710678118654752f));
                        ((__hip_bfloat16*)outp)[idx] = __float2bfloat16(gv);
                    }
                }
            }
        }
    }
}

// ---------------- Flash attention v2.2 ----------------
// grid: (S/256, B*H); block 256 (4 waves); wave owns 64 q rows; KV tile = 64.
// Swapped QK^T, exp2-domain softmax (log2e folded into Q scale), defer-max,
// cvt_pk bf16 pack, setprio around MFMA, K/V dbuf via global_load_lds,
// all LDS tiles 128B-stride + XOR-16B-block swizzle. XCD swizzle: 8 heads/XCD.
__global__ __launch_bounds__(256, 2)
void attn_flash2(const __hip_bfloat16* __restrict__ Q,
                 const __hip_bfloat16* __restrict__ K,
                 const __hip_bfloat16* __restrict__ VT,   // [b][h][dh][s]
                 const unsigned char* __restrict__ kpm,
                 __hip_bfloat16* __restrict__ O)
{
    __shared__ __hip_bfloat16 Ks[2][64 * 64];
    __shared__ __hip_bfloat16 VTs[2][64 * 64];
    __shared__ __hip_bfloat16 Plds[4][64 * 64];

    const int tid = threadIdx.x;
    const int lane = tid & 63;
    const int w = tid >> 6;
    const int g = lane >> 4, lr = lane & 15;

    // XCD swizzle: each XCD owns 8 consecutive heads (all their q-blocks) -> K/V L2 reuse
    const int orig = blockIdx.y * 8 + blockIdx.x;
    const int nl = (orig & 7) * 64 + (orig >> 3);
    const int qb = nl & 7;
    const int bh = nl >> 3;

    const int b = bh >> 4, h = bh & 15;
    const int q0 = qb * 256 + w * 64;
    const size_t tokbase = (size_t)b * 2048;
    const __hip_bfloat16* VTbh = VT + (size_t)bh * 64 * 2048;

    // Q fragments: B-operand of swapped QK^T: Q[q=qn*16+lr][d=f*32+g*8+j]
    bf16x8 qf[4][2];
#pragma unroll
    for (int qn = 0; qn < 4; ++qn)
#pragma unroll
        for (int f = 0; f < 2; ++f)
            qf[qn][f] = *(const bf16x8*)(Q + (tokbase + q0 + qn * 16 + lr) * 1024 +
                                         h * 64 + f * 32 + g * 8);

    f32x4 o[4][4];   // [qa][nd]: O[q=qa*16+g*4+r][d=nd*16+lr]
    const f32x4 zero = {0.f, 0.f, 0.f, 0.f};
#pragma unroll
    for (int qa = 0; qa < 4; ++qa)
#pragma unroll
        for (int nd = 0; nd < 4; ++nd) o[qa][nd] = zero;
    float m_run[4], l_part[4];   // per-lane stats for q = qn*16+lr (log2 domain)
#pragma unroll
    for (int qn = 0; qn < 4; ++qn) { m_run[qn] = -1e30f; l_part[qn] = 0.f; }

    __hip_bfloat16* Pw = Plds[w];
    const int rowl = lane >> 3;       // staging: row within 8-row group
    const int blkp = lane & 7;        // staging: 16B block position in row

    // stage K tile [64 key][64 d] and VT tile [64 d][64 s] (both 128B rows),
    // linear LDS dest, XOR-swizzled global source block.
    auto stage = [&](int bufi, int kv0) {
#pragma unroll
        for (int iss = 0; iss < 2; ++iss) {
            const int row = w * 16 + iss * 8 + rowl;
            const int sblk = blkp ^ (row & 7);
            gload_lds16(K + (tokbase + kv0 + row) * 1024 + h * 64 + sblk * 8,
                        (char*)&Ks[bufi][(w * 16 + iss * 8) * 64] + (lane & 63) * 16);
            gload_lds16(VTbh + (size_t)row * 2048 + kv0 + sblk * 8,
                        (char*)&VTs[bufi][(w * 16 + iss * 8) * 64] + (lane & 63) * 16);
        }
    };

    stage(0, 0);
    __syncthreads();
    int buf = 0;

    for (int t = 0; t < 32; ++t) {
        const int kv0 = t * 64;
        if (t < 31) stage(buf ^ 1, kv0 + 64);

        // ---- S^T = K * Q^T: st[km][qn], lane holds S[key=km*16+g*4+r][q=qn*16+lr]
        f32x4 st[4][4];
        __builtin_amdgcn_s_setprio(1);
#pragma unroll
        for (int km = 0; km < 4; ++km) {
            bf16x8 kf[2];
#pragma unroll
            for (int f = 0; f < 2; ++f)
                kf[f] = *(const bf16x8*)(&Ks[buf][(km * 16 + lr) * 64 +
                                                  (((f * 4 + g) ^ (lr & 7)) * 8)]);
#pragma unroll
            for (int qn = 0; qn < 4; ++qn) {
                st[km][qn] = __builtin_amdgcn_mfma_f32_16x16x32_bf16(kf[0], qf[qn][0], zero, 0, 0, 0);
                st[km][qn] = __builtin_amdgcn_mfma_f32_16x16x32_bf16(kf[1], qf[qn][1], st[km][qn], 0, 0, 0);
            }
        }
        __builtin_amdgcn_s_setprio(0);

        // ---- key padding mask (rare path; all-false in this workload)
#pragma unroll
        for (int km = 0; km < 4; ++km) {
            const unsigned mu = *(const unsigned*)(kpm + tokbase + kv0 + km * 16 + g * 4);
            if (__any((int)(mu != 0u))) {
                const float NEG = -1e30f;
#pragma unroll
                for (int r = 0; r < 4; ++r) {
                    if ((mu >> (8 * r)) & 0xFFu) {
#pragma unroll
                        for (int qn = 0; qn < 4; ++qn) st[km][qn][r] = NEG;
                    }
                }
            }
        }

        // ---- defer-max online softmax (log2 domain)
        float pm[4];
#pragma unroll
        for (int qn = 0; qn < 4; ++qn) {
            float a0 = fmaxf(fmaxf(st[0][qn][0], st[0][qn][1]), fmaxf(st[0][qn][2], st[0][qn][3]));
            float a1 = fmaxf(fmaxf(st[1][qn][0], st[1][qn][1]), fmaxf(st[1][qn][2], st[1][qn][3]));
            float a2 = fmaxf(fmaxf(st[2][qn][0], st[2][qn][1]), fmaxf(st[2][qn][2], st[2][qn][3]));
            float a3 = fmaxf(fmaxf(st[3][qn][0], st[3][qn][1]), fmaxf(st[3][qn][2], st[3][qn][3]));
            pm[qn] = fmaxf(fmaxf(a0, a1), fmaxf(a2, a3));
        }
        const int trig = (pm[0] > m_run[0] + 8.f) | (pm[1] > m_run[1] + 8.f) |
                         (pm[2] > m_run[2] + 8.f) | (pm[3] > m_run[3] + 8.f);
        if (__any(trig)) {
            float alpha_q[4];
#pragma unroll
            for (int qn = 0; qn < 4; ++qn) {
                float rm = pm[qn];
                rm = fmaxf(rm, __shfl_xor(rm, 16));
                rm = fmaxf(rm, __shfl_xor(rm, 32));
                const float mnew = fmaxf(m_run[qn], rm);
                const float al = fexp2(m_run[qn] - mnew);
                l_part[qn] *= al;
                m_run[qn] = mnew;
                alpha_q[qn] = al;
            }
#pragma unroll
            for (int qa = 0; qa < 4; ++qa)
#pragma unroll
                for (int r = 0; r < 4; ++r) {
                    const float av = __shfl(alpha_q[qa], g * 4 + r, 16);
#pragma unroll
                    for (int nd = 0; nd < 4; ++nd) o[qa][nd][r] *= av;
                }
        }

        // ---- P = exp2(S - m), accumulate l, cvt_pk to bf16, b64 store to Plds[q][k]
#pragma unroll
        for (int qn = 0; qn < 4; ++qn) {
            const float mm = m_run[qn];
#pragma unroll
            for (int km = 0; km < 4; ++km) {
                const float p0 = fexp2(st[km][qn][0] - mm);
                const float p1 = fexp2(st[km][qn][1] - mm);
                const float p2 = fexp2(st[km][qn][2] - mm);
                const float p3 = fexp2(st[km][qn][3] - mm);
                l_part[qn] += (p0 + p1) + (p2 + p3);
                uint2 pk;
                pk.x = cvtpk_bf16(p0, p1);
                pk.y = cvtpk_bf16(p2, p3);
                const int cs = (km * 2 + (g >> 1)) ^ (lr & 7);
                *(uint2*)(Pw + (qn * 16 + lr) * 64 + cs * 8 + (g & 1) * 4) = pk;
            }
        }

        // ---- O += P * V
        __builtin_amdgcn_s_setprio(1);
#pragma unroll
        for (int f = 0; f < 2; ++f) {
            bf16x8 pa[4];
#pragma unroll
            for (int qa = 0; qa < 4; ++qa)
                pa[qa] = *(const bf16x8*)(Pw + (qa * 16 + lr) * 64 +
                                          (((f * 4 + g) ^ (lr & 7)) * 8));
#pragma unroll
            for (int nd = 0; nd < 4; ++nd) {
                bf16x8 vb = *(const bf16x8*)(&VTs[buf][(nd * 16 + lr) * 64 +
                                                       (((f * 4 + g) ^ (lr & 7)) * 8)]);
#pragma unroll
                for (int qa = 0; qa < 4; ++qa)
                    o[qa][nd] = __builtin_amdgcn_mfma_f32_16x16x32_bf16(pa[qa], vb, o[qa][nd], 0, 0, 0);
            }
        }
        __builtin_amdgcn_s_setprio(0);

        __syncthreads();
        buf ^= 1;
    }

    // ---- epilogue: 1/l scaling + store
    float linv[4];
#pragma unroll
    for (int qn = 0; qn < 4; ++qn) {
        float lt = l_part[qn];
        lt += __shfl_xor(lt, 16);
        lt += __shfl_xor(lt, 32);
        linv[qn] = 1.0f / lt;
    }
#pragma unroll
    for (int qa = 0; qa < 4; ++qa)
#pragma unroll
        for (int r = 0; r < 4; ++r) {
            const float lv = __shfl(linv[qa], g * 4 + r, 16);
            const size_t row = tokbase + q0 + qa * 16 + g * 4 + r;
#pragma unroll
            for (int nd = 0; nd < 4; ++nd)
                O[row * 1024 + h * 64 + nd * 16 + lr] = __float2bfloat16(o[qa][nd][r] * lv);
        }
}

// ---------------- LayerNorm (row = 1024 floats) ----------------
__global__ __launch_bounds__(256)
void ln_kernel(const float* __restrict__ in, const float* __restrict__ gamma,
               const float* __restrict__ beta, float* __restrict__ outf,
               __hip_bfloat16* __restrict__ outb)
{
    const int row = blockIdx.x;
    const int tid = threadIdx.x;
    float4 v = ((const float4*)(in + (size_t)row * 1024))[tid];
    float s = v.x + v.y + v.z + v.w;
    float s2 = v.x * v.x + v.y * v.y + v.z * v.z + v.w * v.w;
#pragma unroll
    for (int off = 1; off < 64; off <<= 1) {
        s += __shfl_xor(s, off);
        s2 += __shfl_xor(s2, off);
    }
    __shared__ float red[8];
    const int wv = tid >> 6;
    if ((tid & 63) == 0) { red[wv] = s; red[4 + wv] = s2; }
    __syncthreads();
    s = red[0] + red[1] + red[2] + red[3];
    s2 = red[4] + red[5] + red[6] + red[7];
    const float mean = s * (1.f / 1024.f);
    const float var = s2 * (1.f / 1024.f) - mean * mean;
    const float rstd = rsqrtf(var + 1e-5f);
    float4 gm = ((const float4*)gamma)[tid];
    float4 bt = ((const float4*)beta)[tid];
    float4 y;
    y.x = (v.x - mean) * rstd * gm.x + bt.x;
    y.y = (v.y - mean) * rstd * gm.y + bt.y;
    y.z = (v.z - mean) * rstd * gm.z + bt.z;
    y.w = (v.w - mean) * rstd * gm.w + bt.w;
    ((float4*)(outf + (size_t)row * 1024))[tid] = y;
    if (outb) {
        ushort4 ub;
        ub.x = f2bfu(y.x); ub.y = f2bfu(y.y); ub.z = f2bfu(y.z); ub.w = f2bfu(y.w);
        ((ushort4*)outb)[row * 256 + tid] = ub;
    }
}

// ---------------- host ----------------
extern "C" void kernel_launch(void* const* d_in, const int* in_sizes, int n_in,
                              void* d_out, int out_size, void* d_ws, size_t ws_size,
                              hipStream_t stream)
{
    const float* x    = (const float*)d_in[0];
    const unsigned char* kpm = (const unsigned char*)d_in[1];
    const float* Wq = (const float*)d_in[2];
    const float* bq = (const float*)d_in[3];
    const float* Wk = (const float*)d_in[4];
    const float* bk = (const float*)d_in[5];
    const float* Wv = (const float*)d_in[6];
    const float* bv = (const float*)d_in[7];
    const float* Wo = (const float*)d_in[8];
    const float* bo = (const float*)d_in[9];
    const float* W1 = (const float*)d_in[10];
    const float* b1 = (const float*)d_in[11];
    const float* W2 = (const float*)d_in[12];
    const float* b2 = (const float*)d_in[13];
    const float* ln1g = (const float*)d_in[14];
    const float* ln1b = (const float*)d_in[15];
    const float* ln2g = (const float*)d_in[16];
    const float* ln2b = (const float*)d_in[17];
    float* out = (float*)d_out;

    char* ws = (char*)d_ws;
    const size_t SZ_ND2 = (size_t)8192 * 1024 * 2;   // 16.8 MB
    size_t off = 0;
    __hip_bfloat16* xb  = (__hip_bfloat16*)(ws + off); off += SZ_ND2;
    __hip_bfloat16* wqb = (__hip_bfloat16*)(ws + off); off += (size_t)1024 * 1024 * 2;
    __hip_bfloat16* wkb = (__hip_bfloat16*)(ws + off); off += (size_t)1024 * 1024 * 2;
    __hip_bfloat16* wvb = (__hip_bfloat16*)(ws + off); off += (size_t)1024 * 1024 * 2;
    __hip_bfloat16* wob = (__hip_bfloat16*)(ws + off); off += (size_t)1024 * 1024 * 2;
    __hip_bfloat16* w1b = (__hip_bfloat16*)(ws + off); off += (size_t)4096 * 1024 * 2;
    __hip_bfloat16* w2b = (__hip_bfloat16*)(ws + off); off += (size_t)4096 * 1024 * 2;
    const size_t qkv0 = off;
    __hip_bfloat16* qbp = (__hip_bfloat16*)(ws + off); off += SZ_ND2;
    __hip_bfloat16* kbp = (__hip_bfloat16*)(ws + off); off += SZ_ND2;
    __hip_bfloat16* vtg = (__hip_bfloat16*)(ws + off); off += SZ_ND2;  // [b][h][dh][s]
    __hip_bfloat16* abp = (__hip_bfloat16*)(ws + off); off += SZ_ND2;
    __hip_bfloat16* hbp = (__hip_bfloat16*)(ws + qkv0);  // aliases q/k/vt/a (dead by then)
    float* y1 = (float*)(ws + off); off += (size_t)8192 * 1024 * 4;
    float* x1 = (float*)(ws + off); off += (size_t)8192 * 1024 * 4;
    __hip_bfloat16* x1b = (__hip_bfloat16*)(ws + off); off += SZ_ND2;
    float* y2 = y1;

    auto cvt = [&](const float* src, void* dst, int n) {
        cvt_bf16_kernel<<<n / 1024, 256, 0, stream>>>((const float4*)src, (ushort4*)dst, n / 4);
    };
    cvt(x,  xb,  8192 * 1024);
    cvt(Wq, wqb, 1024 * 1024);
    cvt(Wk, wkb, 1024 * 1024);
    cvt(Wv, wvb, 1024 * 1024);
    cvt(Wo, wob, 1024 * 1024);
    cvt(W1, w1b, 4096 * 1024);
    cvt(W2, w2b, 4096 * 1024);

    dim3 blk(256);
    dim3 gD(64, 8);    // M/128 x 1024/128
    dim3 gF(64, 32);   // M/128 x 4096/128

    // Q scale folds softmax's log2(e) so attention works in exp2 domain.
    const float qscale = 0.125f * 1.44269504088896f;
    gemm_bt<EPI_QSCALE><<<gD, blk, 0, stream>>>(xb, wqb, bq, nullptr, qscale, qbp, 8192, 1024, 1024);
    gemm_bt<EPI_BF16>  <<<gD, blk, 0, stream>>>(xb, wkb, bk, nullptr, 1.0f,   kbp, 8192, 1024, 1024);
    gemm_bt<EPI_VT>    <<<gD, blk, 0, stream>>>(xb, wvb, bv, nullptr, 1.0f,   vtg, 8192, 1024, 1024);

    attn_flash2<<<dim3(8, 64), blk, 0, stream>>>(qbp, kbp, vtg, kpm, abp);

    gemm_bt<EPI_RESF32><<<gD, blk, 0, stream>>>(abp, wob, bo, x, 1.0f, y1, 8192, 1024, 1024);
    ln_kernel<<<8192, 256, 0, stream>>>(y1, ln1g, ln1b, x1, x1b);

    gemm_bt<EPI_GELU>  <<<gF, blk, 0, stream>>>(x1b, w1b, b1, nullptr, 1.0f, hbp, 8192, 4096, 1024);
    gemm_bt<EPI_RESF32><<<gD, blk, 0, stream>>>(hbp, w2b, b2, x1, 1.0f, y2, 8192, 1024, 4096);
    ln_kernel<<<8192, 256, 0, stream>>>(y2, ln2g, ln2b, out, nullptr);
}

// Round 5
// 463.520 us; speedup vs baseline: 1.1183x; 1.0198x over previous
//
#include <hip/hip_runtime.h>
#include <hip/hip_bf16.h>
#include <math.h>

typedef short bf16x8 __attribute__((ext_vector_type(8)));
typedef float f32x4 __attribute__((ext_vector_type(4)));

__device__ __forceinline__ unsigned short f2bfu(float f) {
    __hip_bfloat16 h = __float2bfloat16(f);
    return __builtin_bit_cast(unsigned short, h);
}

__device__ __forceinline__ float fexp2(float x) {
    float r;
    asm("v_exp_f32 %0, %1" : "=v"(r) : "v"(x));
    return r;
}

__device__ __forceinline__ unsigned cvtpk_bf16(float lo, float hi) {
    unsigned r;
    asm("v_cvt_pk_bf16_f32 %0, %1, %2" : "=v"(r) : "v"(lo), "v"(hi));
    return r;
}

__device__ __forceinline__ void gload_lds16(const void* gsrc, void* ldst) {
    __builtin_amdgcn_global_load_lds((const __attribute__((address_space(1))) void*)gsrc,
                                     (__attribute__((address_space(3))) void*)ldst,
                                     16, 0, 0);
}

// ---------------- f32 -> bf16 convert ----------------
__global__ __launch_bounds__(256)
void cvt_bf16_kernel(const float4* __restrict__ in, ushort4* __restrict__ out, int n4) {
    int i = blockIdx.x * 256 + threadIdx.x;
    if (i >= n4) return;
    float4 v = in[i];
    ushort4 o;
    o.x = f2bfu(v.x); o.y = f2bfu(v.y); o.z = f2bfu(v.z); o.w = f2bfu(v.w);
    out[i] = o;
}

// ---------------- BT GEMM: C[M,N] = A[M,K] * W[N,K]^T + bias ----------------
// 128x128 tile, BK=32, 2-phase double-buffered staging (T3-minimum):
// issue stage(t+1) early, compute tile t, single barrier per K-step.
enum { EPI_QKV = 0, EPI_RESF32 = 2, EPI_GELU = 3, EPI_RESBF16 = 5 };

template<int EPI>
__global__ __launch_bounds__(256, 2)
void gemm_bt(const __hip_bfloat16* __restrict__ A,
             const __hip_bfloat16* __restrict__ W,
             const float* __restrict__ bias,
             const void* __restrict__ resv,
             float scale,
             void* __restrict__ outp, void* __restrict__ outp2, void* __restrict__ outp3,
             int M, int N, int K)
{
    __shared__ __hip_bfloat16 As[2][128 * 32];
    __shared__ __hip_bfloat16 Ws[2][128 * 32];
    const int tid = threadIdx.x;
    const int lane = tid & 63;
    const int wid = tid >> 6;
    const int wr = wid >> 1, wc = wid & 1;
    const int g = lane >> 4, lr = lane & 15;
    const int row0 = blockIdx.x * 128;
    const int col0 = blockIdx.y * 128;

    f32x4 acc[4][4];
    const f32x4 zero = {0.f, 0.f, 0.f, 0.f};
#pragma unroll
    for (int m = 0; m < 4; ++m)
#pragma unroll
        for (int n = 0; n < 4; ++n) acc[m][n] = zero;

    const int c0 = tid, c1 = tid + 256;
    const int ar0 = c0 >> 2, ac0 = (c0 & 3) * 8;
    const int ar1 = c1 >> 2, ac1 = (c1 & 3) * 8;

    auto stage = [&](int bi, int k0) {
        gload_lds16(A + (size_t)(row0 + ar0) * K + k0 + ac0, (char*)As[bi] + c0 * 16);
        gload_lds16(A + (size_t)(row0 + ar1) * K + k0 + ac1, (char*)As[bi] + c1 * 16);
        gload_lds16(W + (size_t)(col0 + ar0) * K + k0 + ac0, (char*)Ws[bi] + c0 * 16);
        gload_lds16(W + (size_t)(col0 + ar1) * K + k0 + ac1, (char*)Ws[bi] + c1 * 16);
    };

    stage(0, 0);
    __syncthreads();   // compiler drains vmcnt(0) before barrier -> tile 0 ready
    int buf = 0;
    const int NT = K >> 5;

    for (int t = 0; t < NT; ++t) {
        if (t + 1 < NT) stage(buf ^ 1, (t + 1) * 32);   // issue-early prefetch
        bf16x8 af[4], wf[4];
#pragma unroll
        for (int m = 0; m < 4; ++m)
            af[m] = *(const bf16x8*)(As[buf] + (wr * 64 + m * 16 + lr) * 32 + g * 8);
#pragma unroll
        for (int n = 0; n < 4; ++n)
            wf[n] = *(const bf16x8*)(Ws[buf] + (wc * 64 + n * 16 + lr) * 32 + g * 8);
#pragma unroll
        for (int m = 0; m < 4; ++m)
#pragma unroll
            for (int n = 0; n < 4; ++n)
                acc[m][n] = __builtin_amdgcn_mfma_f32_16x16x32_bf16(af[m], wf[n], acc[m][n], 0, 0, 0);
        __syncthreads();   // drains prefetch (issued ~whole iteration earlier) + LDS reuse fence
        buf ^= 1;
    }

#pragma unroll
    for (int n = 0; n < 4; ++n) {
        const int cc = col0 + wc * 64 + n * 16 + lr;
        const float bv = bias[cc];
#pragma unroll
        for (int m = 0; m < 4; ++m) {
            const int rbase = row0 + wr * 64 + m * 16 + g * 4;
            if (EPI == EPI_QKV) {
                const int seg = col0 >> 10;   // 0=Q, 1=K, 2=V (uniform per block)
                if (seg == 2) {
                    // V: write transposed [b][h][dh][s], pack 4 consecutive tokens
                    ushort4 u;
                    u.x = f2bfu(acc[m][n][0] + bv);
                    u.y = f2bfu(acc[m][n][1] + bv);
                    u.z = f2bfu(acc[m][n][2] + bv);
                    u.w = f2bfu(acc[m][n][3] + bv);
                    const int cc2 = cc - 2048;
                    const int h_ = cc2 >> 6, dh = cc2 & 63;
                    const int bb = rbase >> 11;
                    const int s = rbase & 2047;
                    *(ushort4*)((__hip_bfloat16*)outp3 +
                                (((size_t)bb * 16 + h_) * 64 + dh) * 2048 + s) = u;
                } else {
                    const float sc = (seg == 0) ? scale : 1.0f;
                    __hip_bfloat16* dst = (seg == 0) ? (__hip_bfloat16*)outp
                                                     : (__hip_bfloat16*)outp2;
                    const int ccl = cc & 1023;
#pragma unroll
                    for (int r = 0; r < 4; ++r)
                        dst[(size_t)(rbase + r) * 1024 + ccl] =
                            __float2bfloat16((acc[m][n][r] + bv) * sc);
                }
            } else {
#pragma unroll
                for (int r = 0; r < 4; ++r) {
                    const size_t idx = (size_t)(rbase + r) * N + cc;
                    float v = acc[m][n][r] + bv;
                    if (EPI == EPI_RESF32) {
                        ((float*)outp)[idx] = v + ((const float*)resv)[idx];
                    } else if (EPI == EPI_RESBF16) {
                        ((float*)outp)[idx] = v +
                            __bfloat162float(((const __hip_bfloat16*)resv)[idx]);
                    } else if (EPI == EPI_GELU) {
                        float gv = 0.5f * v * (1.0f + erff(v * 0.70710678118654752f));
                        ((__hip_bfloat16*)outp)[idx] = __float2bfloat16(gv);
                    }
                }
            }
        }
    }
}

// ---------------- Flash attention v2.3 ----------------
// grid: (S/256, B*H); block 256 (4 waves); wave owns 64 q rows; KV tile = 64.
// Swapped QK^T, exp2-domain softmax, defer-max, cvt_pk bf16 pack, setprio,
// K/V dbuf via global_load_lds, XOR-16B-block LDS swizzle, XCD head grouping.
__global__ __launch_bounds__(256, 2)
void attn_flash2(const __hip_bfloat16* __restrict__ Q,
                 const __hip_bfloat16* __restrict__ K,
                 const __hip_bfloat16* __restrict__ VT,   // [b][h][dh][s]
                 const unsigned char* __restrict__ kpm,
                 __hip_bfloat16* __restrict__ O)
{
    __shared__ __hip_bfloat16 Ks[2][64 * 64];
    __shared__ __hip_bfloat16 VTs[2][64 * 64];
    __shared__ __hip_bfloat16 Plds[4][64 * 64];

    const int tid = threadIdx.x;
    const int lane = tid & 63;
    const int w = tid >> 6;
    const int g = lane >> 4, lr = lane & 15;

    // XCD swizzle: each XCD owns 8 consecutive heads -> K/V L2 reuse
    const int orig = blockIdx.y * 8 + blockIdx.x;
    const int nl = (orig & 7) * 64 + (orig >> 3);
    const int qb = nl & 7;
    const int bh = nl >> 3;

    const int b = bh >> 4, h = bh & 15;
    const int q0 = qb * 256 + w * 64;
    const size_t tokbase = (size_t)b * 2048;
    const __hip_bfloat16* VTbh = VT + (size_t)bh * 64 * 2048;

    bf16x8 qf[4][2];
#pragma unroll
    for (int qn = 0; qn < 4; ++qn)
#pragma unroll
        for (int f = 0; f < 2; ++f)
            qf[qn][f] = *(const bf16x8*)(Q + (tokbase + q0 + qn * 16 + lr) * 1024 +
                                         h * 64 + f * 32 + g * 8);

    f32x4 o[4][4];   // [qa][nd]: O[q=qa*16+g*4+r][d=nd*16+lr]
    const f32x4 zero = {0.f, 0.f, 0.f, 0.f};
#pragma unroll
    for (int qa = 0; qa < 4; ++qa)
#pragma unroll
        for (int nd = 0; nd < 4; ++nd) o[qa][nd] = zero;
    float m_run[4], l_part[4];   // per-lane stats for q = qn*16+lr (log2 domain)
#pragma unroll
    for (int qn = 0; qn < 4; ++qn) { m_run[qn] = -1e30f; l_part[qn] = 0.f; }

    __hip_bfloat16* Pw = Plds[w];
    const int rowl = lane >> 3;
    const int blkp = lane & 7;

    auto stage = [&](int bufi, int kv0) {
#pragma unroll
        for (int iss = 0; iss < 2; ++iss) {
            const int row = w * 16 + iss * 8 + rowl;
            const int sblk = blkp ^ (row & 7);
            gload_lds16(K + (tokbase + kv0 + row) * 1024 + h * 64 + sblk * 8,
                        (char*)&Ks[bufi][(w * 16 + iss * 8) * 64] + (lane & 63) * 16);
            gload_lds16(VTbh + (size_t)row * 2048 + kv0 + sblk * 8,
                        (char*)&VTs[bufi][(w * 16 + iss * 8) * 64] + (lane & 63) * 16);
        }
    };

    stage(0, 0);
    __syncthreads();
    int buf = 0;

    for (int t = 0; t < 32; ++t) {
        const int kv0 = t * 64;
        if (t < 31) stage(buf ^ 1, kv0 + 64);

        // ---- S^T = K * Q^T
        f32x4 st[4][4];
        __builtin_amdgcn_s_setprio(1);
#pragma unroll
        for (int km = 0; km < 4; ++km) {
            bf16x8 kf[2];
#pragma unroll
            for (int f = 0; f < 2; ++f)
                kf[f] = *(const bf16x8*)(&Ks[buf][(km * 16 + lr) * 64 +
                                                  (((f * 4 + g) ^ (lr & 7)) * 8)]);
#pragma unroll
            for (int qn = 0; qn < 4; ++qn) {
                st[km][qn] = __builtin_amdgcn_mfma_f32_16x16x32_bf16(kf[0], qf[qn][0], zero, 0, 0, 0);
                st[km][qn] = __builtin_amdgcn_mfma_f32_16x16x32_bf16(kf[1], qf[qn][1], st[km][qn], 0, 0, 0);
            }
        }
        __builtin_amdgcn_s_setprio(0);

        // ---- key padding mask: one wave-wide check per tile (all-false fast path)
        if (__any((int)(kpm[tokbase + kv0 + lane] != 0))) {
            const float NEG = -1e30f;
#pragma unroll
            for (int km = 0; km < 4; ++km) {
                const unsigned mu = *(const unsigned*)(kpm + tokbase + kv0 + km * 16 + g * 4);
#pragma unroll
                for (int r = 0; r < 4; ++r) {
                    if ((mu >> (8 * r)) & 0xFFu) {
#pragma unroll
                        for (int qn = 0; qn < 4; ++qn) st[km][qn][r] = NEG;
                    }
                }
            }
        }

        // ---- defer-max online softmax (log2 domain)
        float pm[4];
#pragma unroll
        for (int qn = 0; qn < 4; ++qn) {
            float a0 = fmaxf(fmaxf(st[0][qn][0], st[0][qn][1]), fmaxf(st[0][qn][2], st[0][qn][3]));
            float a1 = fmaxf(fmaxf(st[1][qn][0], st[1][qn][1]), fmaxf(st[1][qn][2], st[1][qn][3]));
            float a2 = fmaxf(fmaxf(st[2][qn][0], st[2][qn][1]), fmaxf(st[2][qn][2], st[2][qn][3]));
            float a3 = fmaxf(fmaxf(st[3][qn][0], st[3][qn][1]), fmaxf(st[3][qn][2], st[3][qn][3]));
            pm[qn] = fmaxf(fmaxf(a0, a1), fmaxf(a2, a3));
        }
        const int trig = (pm[0] > m_run[0] + 8.f) | (pm[1] > m_run[1] + 8.f) |
                         (pm[2] > m_run[2] + 8.f) | (pm[3] > m_run[3] + 8.f);
        if (__any(trig)) {
            float alpha_q[4];
#pragma unroll
            for (int qn = 0; qn < 4; ++qn) {
                float rm = pm[qn];
                rm = fmaxf(rm, __shfl_xor(rm, 16));
                rm = fmaxf(rm, __shfl_xor(rm, 32));
                const float mnew = fmaxf(m_run[qn], rm);
                const float al = fexp2(m_run[qn] - mnew);
                l_part[qn] *= al;
                m_run[qn] = mnew;
                alpha_q[qn] = al;
            }
#pragma unroll
            for (int qa = 0; qa < 4; ++qa)
#pragma unroll
                for (int r = 0; r < 4; ++r) {
                    const float av = __shfl(alpha_q[qa], g * 4 + r, 16);
#pragma unroll
                    for (int nd = 0; nd < 4; ++nd) o[qa][nd][r] *= av;
                }
        }

        // ---- P = exp2(S - m), accumulate l, cvt_pk to bf16, b64 store
#pragma unroll
        for (int qn = 0; qn < 4; ++qn) {
            const float mm = m_run[qn];
#pragma unroll
            for (int km = 0; km < 4; ++km) {
                const float p0 = fexp2(st[km][qn][0] - mm);
                const float p1 = fexp2(st[km][qn][1] - mm);
                const float p2 = fexp2(st[km][qn][2] - mm);
                const float p3 = fexp2(st[km][qn][3] - mm);
                l_part[qn] += (p0 + p1) + (p2 + p3);
                uint2 pk;
                pk.x = cvtpk_bf16(p0, p1);
                pk.y = cvtpk_bf16(p2, p3);
                const int cs = (km * 2 + (g >> 1)) ^ (lr & 7);
                *(uint2*)(Pw + (qn * 16 + lr) * 64 + cs * 8 + (g & 1) * 4) = pk;
            }
        }

        // ---- O += P * V
        __builtin_amdgcn_s_setprio(1);
#pragma unroll
        for (int f = 0; f < 2; ++f) {
            bf16x8 pa[4];
#pragma unroll
            for (int qa = 0; qa < 4; ++qa)
                pa[qa] = *(const bf16x8*)(Pw + (qa * 16 + lr) * 64 +
                                          (((f * 4 + g) ^ (lr & 7)) * 8));
#pragma unroll
            for (int nd = 0; nd < 4; ++nd) {
                bf16x8 vb = *(const bf16x8*)(&VTs[buf][(nd * 16 + lr) * 64 +
                                                       (((f * 4 + g) ^ (lr & 7)) * 8)]);
#pragma unroll
                for (int qa = 0; qa < 4; ++qa)
                    o[qa][nd] = __builtin_amdgcn_mfma_f32_16x16x32_bf16(pa[qa], vb, o[qa][nd], 0, 0, 0);
            }
        }
        __builtin_amdgcn_s_setprio(0);

        __syncthreads();
        buf ^= 1;
    }

    // ---- epilogue
    float linv[4];
#pragma unroll
    for (int qn = 0; qn < 4; ++qn) {
        float lt = l_part[qn];
        lt += __shfl_xor(lt, 16);
        lt += __shfl_xor(lt, 32);
        linv[qn] = 1.0f / lt;
    }
#pragma unroll
    for (int qa = 0; qa < 4; ++qa)
#pragma unroll
        for (int r = 0; r < 4; ++r) {
            const float lv = __shfl(linv[qa], g * 4 + r, 16);
            const size_t row = tokbase + q0 + qa * 16 + g * 4 + r;
#pragma unroll
            for (int nd = 0; nd < 4; ++nd)
                O[row * 1024 + h * 64 + nd * 16 + lr] = __float2bfloat16(o[qa][nd][r] * lv);
        }
}

// ---------------- LayerNorm (row = 1024 floats) ----------------
__global__ __launch_bounds__(256)
void ln_kernel(const float* __restrict__ in, const float* __restrict__ gamma,
               const float* __restrict__ beta, float* __restrict__ outf,
               __hip_bfloat16* __restrict__ outb)
{
    const int row = blockIdx.x;
    const int tid = threadIdx.x;
    float4 v = ((const float4*)(in + (size_t)row * 1024))[tid];
    float s = v.x + v.y + v.z + v.w;
    float s2 = v.x * v.x + v.y * v.y + v.z * v.z + v.w * v.w;
#pragma unroll
    for (int off = 1; off < 64; off <<= 1) {
        s += __shfl_xor(s, off);
        s2 += __shfl_xor(s2, off);
    }
    __shared__ float red[8];
    const int wv = tid >> 6;
    if ((tid & 63) == 0) { red[wv] = s; red[4 + wv] = s2; }
    __syncthreads();
    s = red[0] + red[1] + red[2] + red[3];
    s2 = red[4] + red[5] + red[6] + red[7];
    const float mean = s * (1.f / 1024.f);
    const float var = s2 * (1.f / 1024.f) - mean * mean;
    const float rstd = rsqrtf(var + 1e-5f);
    float4 gm = ((const float4*)gamma)[tid];
    float4 bt = ((const float4*)beta)[tid];
    float4 y;
    y.x = (v.x - mean) * rstd * gm.x + bt.x;
    y.y = (v.y - mean) * rstd * gm.y + bt.y;
    y.z = (v.z - mean) * rstd * gm.z + bt.z;
    y.w = (v.w - mean) * rstd * gm.w + bt.w;
    if (outf) ((float4*)(outf + (size_t)row * 1024))[tid] = y;
    if (outb) {
        ushort4 ub;
        ub.x = f2bfu(y.x); ub.y = f2bfu(y.y); ub.z = f2bfu(y.z); ub.w = f2bfu(y.w);
        ((ushort4*)outb)[row * 256 + tid] = ub;
    }
}

// ---------------- host ----------------
extern "C" void kernel_launch(void* const* d_in, const int* in_sizes, int n_in,
                              void* d_out, int out_size, void* d_ws, size_t ws_size,
                              hipStream_t stream)
{
    const float* x    = (const float*)d_in[0];
    const unsigned char* kpm = (const unsigned char*)d_in[1];
    const float* Wq = (const float*)d_in[2];
    const float* bq = (const float*)d_in[3];
    const float* Wk = (const float*)d_in[4];
    const float* bk = (const float*)d_in[5];
    const float* Wv = (const float*)d_in[6];
    const float* bv = (const float*)d_in[7];
    const float* Wo = (const float*)d_in[8];
    const float* bo = (const float*)d_in[9];
    const float* W1 = (const float*)d_in[10];
    const float* b1 = (const float*)d_in[11];
    const float* W2 = (const float*)d_in[12];
    const float* b2 = (const float*)d_in[13];
    const float* ln1g = (const float*)d_in[14];
    const float* ln1b = (const float*)d_in[15];
    const float* ln2g = (const float*)d_in[16];
    const float* ln2b = (const float*)d_in[17];
    float* out = (float*)d_out;

    char* ws = (char*)d_ws;
    const size_t SZ_ND2 = (size_t)8192 * 1024 * 2;   // 16.8 MB
    size_t off = 0;
    __hip_bfloat16* xb  = (__hip_bfloat16*)(ws + off); off += SZ_ND2;
    // wq/wk/wv contiguous -> one merged [3072,1024] weight for the QKV GEMM
    __hip_bfloat16* wqb = (__hip_bfloat16*)(ws + off); off += (size_t)1024 * 1024 * 2;
    __hip_bfloat16* wkb = (__hip_bfloat16*)(ws + off); off += (size_t)1024 * 1024 * 2;
    __hip_bfloat16* wvb = (__hip_bfloat16*)(ws + off); off += (size_t)1024 * 1024 * 2;
    __hip_bfloat16* wob = (__hip_bfloat16*)(ws + off); off += (size_t)1024 * 1024 * 2;
    __hip_bfloat16* w1b = (__hip_bfloat16*)(ws + off); off += (size_t)4096 * 1024 * 2;
    __hip_bfloat16* w2b = (__hip_bfloat16*)(ws + off); off += (size_t)4096 * 1024 * 2;
    const size_t qkv0 = off;
    __hip_bfloat16* qbp = (__hip_bfloat16*)(ws + off); off += SZ_ND2;
    __hip_bfloat16* kbp = (__hip_bfloat16*)(ws + off); off += SZ_ND2;
    __hip_bfloat16* vtg = (__hip_bfloat16*)(ws + off); off += SZ_ND2;  // [b][h][dh][s]
    __hip_bfloat16* abp = (__hip_bfloat16*)(ws + off); off += SZ_ND2;
    __hip_bfloat16* hbp = (__hip_bfloat16*)(ws + qkv0);  // aliases q/k/vt/a (dead by then)
    float* y1 = (float*)(ws + off); off += (size_t)8192 * 1024 * 4;
    __hip_bfloat16* x1b = (__hip_bfloat16*)(ws + off); off += SZ_ND2;
    float* y2 = y1;

    // bias concat for QKV GEMM: need contiguous [3072] f32 bias
    float* bqkv = (float*)(ws + off); off += 3072 * 4;

    auto cvt = [&](const float* src, void* dst, int n) {
        cvt_bf16_kernel<<<n / 1024, 256, 0, stream>>>((const float4*)src, (ushort4*)dst, n / 4);
    };
    cvt(x,  xb,  8192 * 1024);
    cvt(Wq, wqb, 1024 * 1024);
    cvt(Wk, wkb, 1024 * 1024);
    cvt(Wv, wvb, 1024 * 1024);
    cvt(Wo, wob, 1024 * 1024);
    cvt(W1, w1b, 4096 * 1024);
    cvt(W2, w2b, 4096 * 1024);
    hipMemcpyAsync(bqkv,        bq, 4096, hipMemcpyDeviceToDevice, stream);
    hipMemcpyAsync(bqkv + 1024, bk, 4096, hipMemcpyDeviceToDevice, stream);
    hipMemcpyAsync(bqkv + 2048, bv, 4096, hipMemcpyDeviceToDevice, stream);

    dim3 blk(256);

    // Q scale folds softmax's log2(e) so attention works in exp2 domain.
    const float qscale = 0.125f * 1.44269504088896f;
    gemm_bt<EPI_QKV><<<dim3(64, 24), blk, 0, stream>>>(
        xb, wqb, bqkv, nullptr, qscale, qbp, kbp, vtg, 8192, 3072, 1024);

    attn_flash2<<<dim3(8, 64), blk, 0, stream>>>(qbp, kbp, vtg, kpm, abp);

    gemm_bt<EPI_RESF32><<<dim3(64, 8), blk, 0, stream>>>(
        abp, wob, bo, x, 1.0f, y1, nullptr, nullptr, 8192, 1024, 1024);
    ln_kernel<<<8192, 256, 0, stream>>>(y1, ln1g, ln1b, nullptr, x1b);

    gemm_bt<EPI_GELU><<<dim3(64, 32), blk, 0, stream>>>(
        x1b, w1b, b1, nullptr, 1.0f, hbp, nullptr, nullptr, 8192, 4096, 1024);
    gemm_bt<EPI_RESBF16><<<dim3(64, 8), blk, 0, stream>>>(
        hbp, w2b, b2, x1b, 1.0f, y2, nullptr, nullptr, 8192, 1024, 4096);
    ln_kernel<<<8192, 256, 0, stream>>>(y2, ln2g, ln2b, out, nullptr);
}

// Round 6
// 437.025 us; speedup vs baseline: 1.1861x; 1.0606x over previous
//
#include <hip/hip_runtime.h>
#include <hip/hip_bf16.h>
#include <math.h>

typedef short bf16x8 __attribute__((ext_vector_type(8)));
typedef float f32x4 __attribute__((ext_vector_type(4)));

__device__ __forceinline__ unsigned short f2bfu(float f) {
    __hip_bfloat16 h = __float2bfloat16(f);
    return __builtin_bit_cast(unsigned short, h);
}

__device__ __forceinline__ float fexp2(float x) {
    float r;
    asm("v_exp_f32 %0, %1" : "=v"(r) : "v"(x));
    return r;
}

__device__ __forceinline__ unsigned cvtpk_bf16(float lo, float hi) {
    unsigned r;
    asm("v_cvt_pk_bf16_f32 %0, %1, %2" : "=v"(r) : "v"(lo), "v"(hi));
    return r;
}

// exact-enough GELU: tanh form via exp2 (max err ~3e-4, far under bf16 budget)
__device__ __forceinline__ float gelu_fast(float x) {
    const float x2 = x * x;
    const float z = x * (0.7978845608f + 0.0356774081f * x2); // sqrt(2/pi)*(x+0.044715x^3)
    const float e = fexp2(z * 2.88539008f);                   // exp(2z)
    const float r = __builtin_amdgcn_rcpf(e + 1.0f);
    return x * (1.0f - r);
}

__device__ __forceinline__ void gload_lds16(const void* gsrc, void* ldst) {
    __builtin_amdgcn_global_load_lds((const __attribute__((address_space(1))) void*)gsrc,
                                     (__attribute__((address_space(3))) void*)ldst,
                                     16, 0, 0);
}

// ---------------- f32 -> bf16 convert ----------------
__global__ __launch_bounds__(256)
void cvt_bf16_kernel(const float4* __restrict__ in, ushort4* __restrict__ out, int n4) {
    int i = blockIdx.x * 256 + threadIdx.x;
    if (i >= n4) return;
    float4 v = in[i];
    ushort4 o;
    o.x = f2bfu(v.x); o.y = f2bfu(v.y); o.z = f2bfu(v.z); o.w = f2bfu(v.w);
    out[i] = o;
}

// ---------------- BT GEMM: C[M,N] = A[M,K] * W[N,K]^T + bias ----------------
// 128x128 tile, BK=32, 3-buffer counted-vmcnt pipeline (T4):
// stage tile t+2 at iter t; s_waitcnt vmcnt(4) before raw s_barrier keeps the
// newest 4 loads in flight ACROSS the barrier (only tile t+1 must be landed).
enum { EPI_QKV = 0, EPI_RESF32 = 2, EPI_GELU = 3, EPI_RESBF16 = 5 };

template<int EPI>
__global__ __launch_bounds__(256, 3)
void gemm_bt(const __hip_bfloat16* __restrict__ A,
             const __hip_bfloat16* __restrict__ W,
             const float* __restrict__ bias,
             const void* __restrict__ resv,
             float scale,
             void* __restrict__ outp, void* __restrict__ outp2, void* __restrict__ outp3,
             int M, int N, int K)
{
    __shared__ __hip_bfloat16 As[3][128 * 32];
    __shared__ __hip_bfloat16 Ws[3][128 * 32];
    const int tid = threadIdx.x;
    const int lane = tid & 63;
    const int wid = tid >> 6;
    const int wr = wid >> 1, wc = wid & 1;
    const int g = lane >> 4, lr = lane & 15;
    const int row0 = blockIdx.x * 128;
    const int col0 = blockIdx.y * 128;

    f32x4 acc[4][4];
    const f32x4 zero = {0.f, 0.f, 0.f, 0.f};
#pragma unroll
    for (int m = 0; m < 4; ++m)
#pragma unroll
        for (int n = 0; n < 4; ++n) acc[m][n] = zero;

    const int c0 = tid, c1 = tid + 256;
    const int ar0 = c0 >> 2, ac0 = (c0 & 3) * 8;
    const int ar1 = c1 >> 2, ac1 = (c1 & 3) * 8;
    const __hip_bfloat16* Arow0 = A + (size_t)(row0 + ar0) * K + ac0;
    const __hip_bfloat16* Arow1 = A + (size_t)(row0 + ar1) * K + ac1;
    const __hip_bfloat16* Wrow0 = W + (size_t)(col0 + ar0) * K + ac0;
    const __hip_bfloat16* Wrow1 = W + (size_t)(col0 + ar1) * K + ac1;

    auto stage = [&](int bi, int k0) {
        gload_lds16(Arow0 + k0, (char*)As[bi] + c0 * 16);
        gload_lds16(Arow1 + k0, (char*)As[bi] + c1 * 16);
        gload_lds16(Wrow0 + k0, (char*)Ws[bi] + c0 * 16);
        gload_lds16(Wrow1 + k0, (char*)Ws[bi] + c1 * 16);
    };

    const int NT = K >> 5;
    stage(0, 0);
    stage(1, 32);
    asm volatile("s_waitcnt vmcnt(4)" ::: "memory");   // tile 0 landed; tile 1 in flight
    __builtin_amdgcn_s_barrier();
    __builtin_amdgcn_sched_barrier(0);

    int cur = 0, stg = 2;
    int kpre = 64;
    for (int t = 0; t < NT; ++t) {
        if (t + 2 < NT) stage(stg, kpre);   // overwrites buffer read at t-1 (post-barrier: safe)

        bf16x8 af[4], wf[4];
#pragma unroll
        for (int m = 0; m < 4; ++m)
            af[m] = *(const bf16x8*)(As[cur] + (wr * 64 + m * 16 + lr) * 32 + g * 8);
#pragma unroll
        for (int n = 0; n < 4; ++n)
            wf[n] = *(const bf16x8*)(Ws[cur] + (wc * 64 + n * 16 + lr) * 32 + g * 8);
#pragma unroll
        for (int m = 0; m < 4; ++m)
#pragma unroll
            for (int n = 0; n < 4; ++n)
                acc[m][n] = __builtin_amdgcn_mfma_f32_16x16x32_bf16(af[m], wf[n], acc[m][n], 0, 0, 0);

        if (t + 1 < NT) {
            if (t + 2 < NT) asm volatile("s_waitcnt vmcnt(4)" ::: "memory"); // t+1 landed
            else            asm volatile("s_waitcnt vmcnt(0)" ::: "memory"); // drain tail
            __builtin_amdgcn_s_barrier();
            __builtin_amdgcn_sched_barrier(0);
        }
        cur = (cur == 2) ? 0 : cur + 1;
        stg = (stg == 2) ? 0 : stg + 1;
        kpre += 32;
    }

#pragma unroll
    for (int n = 0; n < 4; ++n) {
        const int cc = col0 + wc * 64 + n * 16 + lr;
        const float bv = bias[cc];
#pragma unroll
        for (int m = 0; m < 4; ++m) {
            const int rbase = row0 + wr * 64 + m * 16 + g * 4;
            if (EPI == EPI_QKV) {
                const int seg = col0 >> 10;   // 0=Q, 1=K, 2=V (uniform per block)
                if (seg == 2) {
                    // V: write transposed [b][h][dh][s], pack 4 consecutive tokens
                    ushort4 u;
                    u.x = f2bfu(acc[m][n][0] + bv);
                    u.y = f2bfu(acc[m][n][1] + bv);
                    u.z = f2bfu(acc[m][n][2] + bv);
                    u.w = f2bfu(acc[m][n][3] + bv);
                    const int cc2 = cc - 2048;
                    const int h_ = cc2 >> 6, dh = cc2 & 63;
                    const int bb = rbase >> 11;
                    const int s = rbase & 2047;
                    *(ushort4*)((__hip_bfloat16*)outp3 +
                                (((size_t)bb * 16 + h_) * 64 + dh) * 2048 + s) = u;
                } else {
                    const float sc = (seg == 0) ? scale : 1.0f;
                    __hip_bfloat16* dst = (seg == 0) ? (__hip_bfloat16*)outp
                                                     : (__hip_bfloat16*)outp2;
                    const int ccl = cc & 1023;
#pragma unroll
                    for (int r = 0; r < 4; ++r)
                        dst[(size_t)(rbase + r) * 1024 + ccl] =
                            __float2bfloat16((acc[m][n][r] + bv) * sc);
                }
            } else {
#pragma unroll
                for (int r = 0; r < 4; ++r) {
                    const size_t idx = (size_t)(rbase + r) * N + cc;
                    float v = acc[m][n][r] + bv;
                    if (EPI == EPI_RESF32) {
                        ((float*)outp)[idx] = v + ((const float*)resv)[idx];
                    } else if (EPI == EPI_RESBF16) {
                        ((float*)outp)[idx] = v +
                            __bfloat162float(((const __hip_bfloat16*)resv)[idx]);
                    } else if (EPI == EPI_GELU) {
                        ((__hip_bfloat16*)outp)[idx] = __float2bfloat16(gelu_fast(v));
                    }
                }
            }
        }
    }
}

// ---------------- Flash attention v2.3 ----------------
// grid: (S/256, B*H); block 256 (4 waves); wave owns 64 q rows; KV tile = 64.
// Swapped QK^T, exp2-domain softmax, defer-max, cvt_pk bf16 pack, setprio,
// K/V dbuf via global_load_lds, XOR-16B-block LDS swizzle, XCD head grouping.
__global__ __launch_bounds__(256, 2)
void attn_flash2(const __hip_bfloat16* __restrict__ Q,
                 const __hip_bfloat16* __restrict__ K,
                 const __hip_bfloat16* __restrict__ VT,   // [b][h][dh][s]
                 const unsigned char* __restrict__ kpm,
                 __hip_bfloat16* __restrict__ O)
{
    __shared__ __hip_bfloat16 Ks[2][64 * 64];
    __shared__ __hip_bfloat16 VTs[2][64 * 64];
    __shared__ __hip_bfloat16 Plds[4][64 * 64];

    const int tid = threadIdx.x;
    const int lane = tid & 63;
    const int w = tid >> 6;
    const int g = lane >> 4, lr = lane & 15;

    // XCD swizzle: each XCD owns 8 consecutive heads -> K/V L2 reuse
    const int orig = blockIdx.y * 8 + blockIdx.x;
    const int nl = (orig & 7) * 64 + (orig >> 3);
    const int qb = nl & 7;
    const int bh = nl >> 3;

    const int b = bh >> 4, h = bh & 15;
    const int q0 = qb * 256 + w * 64;
    const size_t tokbase = (size_t)b * 2048;
    const __hip_bfloat16* VTbh = VT + (size_t)bh * 64 * 2048;

    bf16x8 qf[4][2];
#pragma unroll
    for (int qn = 0; qn < 4; ++qn)
#pragma unroll
        for (int f = 0; f < 2; ++f)
            qf[qn][f] = *(const bf16x8*)(Q + (tokbase + q0 + qn * 16 + lr) * 1024 +
                                         h * 64 + f * 32 + g * 8);

    f32x4 o[4][4];   // [qa][nd]: O[q=qa*16+g*4+r][d=nd*16+lr]
    const f32x4 zero = {0.f, 0.f, 0.f, 0.f};
#pragma unroll
    for (int qa = 0; qa < 4; ++qa)
#pragma unroll
        for (int nd = 0; nd < 4; ++nd) o[qa][nd] = zero;
    float m_run[4], l_part[4];   // per-lane stats for q = qn*16+lr (log2 domain)
#pragma unroll
    for (int qn = 0; qn < 4; ++qn) { m_run[qn] = -1e30f; l_part[qn] = 0.f; }

    __hip_bfloat16* Pw = Plds[w];
    const int rowl = lane >> 3;
    const int blkp = lane & 7;

    auto stage = [&](int bufi, int kv0) {
#pragma unroll
        for (int iss = 0; iss < 2; ++iss) {
            const int row = w * 16 + iss * 8 + rowl;
            const int sblk = blkp ^ (row & 7);
            gload_lds16(K + (tokbase + kv0 + row) * 1024 + h * 64 + sblk * 8,
                        (char*)&Ks[bufi][(w * 16 + iss * 8) * 64] + (lane & 63) * 16);
            gload_lds16(VTbh + (size_t)row * 2048 + kv0 + sblk * 8,
                        (char*)&VTs[bufi][(w * 16 + iss * 8) * 64] + (lane & 63) * 16);
        }
    };

    stage(0, 0);
    __syncthreads();
    int buf = 0;

    for (int t = 0; t < 32; ++t) {
        const int kv0 = t * 64;
        if (t < 31) stage(buf ^ 1, kv0 + 64);

        // ---- S^T = K * Q^T
        f32x4 st[4][4];
        __builtin_amdgcn_s_setprio(1);
#pragma unroll
        for (int km = 0; km < 4; ++km) {
            bf16x8 kf[2];
#pragma unroll
            for (int f = 0; f < 2; ++f)
                kf[f] = *(const bf16x8*)(&Ks[buf][(km * 16 + lr) * 64 +
                                                  (((f * 4 + g) ^ (lr & 7)) * 8)]);
#pragma unroll
            for (int qn = 0; qn < 4; ++qn) {
                st[km][qn] = __builtin_amdgcn_mfma_f32_16x16x32_bf16(kf[0], qf[qn][0], zero, 0, 0, 0);
                st[km][qn] = __builtin_amdgcn_mfma_f32_16x16x32_bf16(kf[1], qf[qn][1], st[km][qn], 0, 0, 0);
            }
        }
        __builtin_amdgcn_s_setprio(0);

        // ---- key padding mask: one wave-wide check per tile (all-false fast path)
        if (__any((int)(kpm[tokbase + kv0 + lane] != 0))) {
            const float NEG = -1e30f;
#pragma unroll
            for (int km = 0; km < 4; ++km) {
                const unsigned mu = *(const unsigned*)(kpm + tokbase + kv0 + km * 16 + g * 4);
#pragma unroll
                for (int r = 0; r < 4; ++r) {
                    if ((mu >> (8 * r)) & 0xFFu) {
#pragma unroll
                        for (int qn = 0; qn < 4; ++qn) st[km][qn][r] = NEG;
                    }
                }
            }
        }

        // ---- defer-max online softmax (log2 domain)
        float pm[4];
#pragma unroll
        for (int qn = 0; qn < 4; ++qn) {
            float a0 = fmaxf(fmaxf(st[0][qn][0], st[0][qn][1]), fmaxf(st[0][qn][2], st[0][qn][3]));
            float a1 = fmaxf(fmaxf(st[1][qn][0], st[1][qn][1]), fmaxf(st[1][qn][2], st[1][qn][3]));
            float a2 = fmaxf(fmaxf(st[2][qn][0], st[2][qn][1]), fmaxf(st[2][qn][2], st[2][qn][3]));
            float a3 = fmaxf(fmaxf(st[3][qn][0], st[3][qn][1]), fmaxf(st[3][qn][2], st[3][qn][3]));
            pm[qn] = fmaxf(fmaxf(a0, a1), fmaxf(a2, a3));
        }
        const int trig = (pm[0] > m_run[0] + 8.f) | (pm[1] > m_run[1] + 8.f) |
                         (pm[2] > m_run[2] + 8.f) | (pm[3] > m_run[3] + 8.f);
        if (__any(trig)) {
            float alpha_q[4];
#pragma unroll
            for (int qn = 0; qn < 4; ++qn) {
                float rm = pm[qn];
                rm = fmaxf(rm, __shfl_xor(rm, 16));
                rm = fmaxf(rm, __shfl_xor(rm, 32));
                const float mnew = fmaxf(m_run[qn], rm);
                const float al = fexp2(m_run[qn] - mnew);
                l_part[qn] *= al;
                m_run[qn] = mnew;
                alpha_q[qn] = al;
            }
#pragma unroll
            for (int qa = 0; qa < 4; ++qa)
#pragma unroll
                for (int r = 0; r < 4; ++r) {
                    const float av = __shfl(alpha_q[qa], g * 4 + r, 16);
#pragma unroll
                    for (int nd = 0; nd < 4; ++nd) o[qa][nd][r] *= av;
                }
        }

        // ---- P = exp2(S - m), accumulate l, cvt_pk to bf16, b64 store
#pragma unroll
        for (int qn = 0; qn < 4; ++qn) {
            const float mm = m_run[qn];
#pragma unroll
            for (int km = 0; km < 4; ++km) {
                const float p0 = fexp2(st[km][qn][0] - mm);
                const float p1 = fexp2(st[km][qn][1] - mm);
                const float p2 = fexp2(st[km][qn][2] - mm);
                const float p3 = fexp2(st[km][qn][3] - mm);
                l_part[qn] += (p0 + p1) + (p2 + p3);
                uint2 pk;
                pk.x = cvtpk_bf16(p0, p1);
                pk.y = cvtpk_bf16(p2, p3);
                const int cs = (km * 2 + (g >> 1)) ^ (lr & 7);
                *(uint2*)(Pw + (qn * 16 + lr) * 64 + cs * 8 + (g & 1) * 4) = pk;
            }
        }

        // ---- O += P * V
        __builtin_amdgcn_s_setprio(1);
#pragma unroll
        for (int f = 0; f < 2; ++f) {
            bf16x8 pa[4];
#pragma unroll
            for (int qa = 0; qa < 4; ++qa)
                pa[qa] = *(const bf16x8*)(Pw + (qa * 16 + lr) * 64 +
                                          (((f * 4 + g) ^ (lr & 7)) * 8));
#pragma unroll
            for (int nd = 0; nd < 4; ++nd) {
                bf16x8 vb = *(const bf16x8*)(&VTs[buf][(nd * 16 + lr) * 64 +
                                                       (((f * 4 + g) ^ (lr & 7)) * 8)]);
#pragma unroll
                for (int qa = 0; qa < 4; ++qa)
                    o[qa][nd] = __builtin_amdgcn_mfma_f32_16x16x32_bf16(pa[qa], vb, o[qa][nd], 0, 0, 0);
            }
        }
        __builtin_amdgcn_s_setprio(0);

        __syncthreads();
        buf ^= 1;
    }

    // ---- epilogue
    float linv[4];
#pragma unroll
    for (int qn = 0; qn < 4; ++qn) {
        float lt = l_part[qn];
        lt += __shfl_xor(lt, 16);
        lt += __shfl_xor(lt, 32);
        linv[qn] = 1.0f / lt;
    }
#pragma unroll
    for (int qa = 0; qa < 4; ++qa)
#pragma unroll
        for (int r = 0; r < 4; ++r) {
            const float lv = __shfl(linv[qa], g * 4 + r, 16);
            const size_t row = tokbase + q0 + qa * 16 + g * 4 + r;
#pragma unroll
            for (int nd = 0; nd < 4; ++nd)
                O[row * 1024 + h * 64 + nd * 16 + lr] = __float2bfloat16(o[qa][nd][r] * lv);
        }
}

// ---------------- LayerNorm (row = 1024 floats) ----------------
__global__ __launch_bounds__(256)
void ln_kernel(const float* __restrict__ in, const float* __restrict__ gamma,
               const float* __restrict__ beta, float* __restrict__ outf,
               __hip_bfloat16* __restrict__ outb)
{
    const int row = blockIdx.x;
    const int tid = threadIdx.x;
    float4 v = ((const float4*)(in + (size_t)row * 1024))[tid];
    float s = v.x + v.y + v.z + v.w;
    float s2 = v.x * v.x + v.y * v.y + v.z * v.z + v.w * v.w;
#pragma unroll
    for (int off = 1; off < 64; off <<= 1) {
        s += __shfl_xor(s, off);
        s2 += __shfl_xor(s2, off);
    }
    __shared__ float red[8];
    const int wv = tid >> 6;
    if ((tid & 63) == 0) { red[wv] = s; red[4 + wv] = s2; }
    __syncthreads();
    s = red[0] + red[1] + red[2] + red[3];
    s2 = red[4] + red[5] + red[6] + red[7];
    const float mean = s * (1.f / 1024.f);
    const float var = s2 * (1.f / 1024.f) - mean * mean;
    const float rstd = rsqrtf(var + 1e-5f);
    float4 gm = ((const float4*)gamma)[tid];
    float4 bt = ((const float4*)beta)[tid];
    float4 y;
    y.x = (v.x - mean) * rstd * gm.x + bt.x;
    y.y = (v.y - mean) * rstd * gm.y + bt.y;
    y.z = (v.z - mean) * rstd * gm.z + bt.z;
    y.w = (v.w - mean) * rstd * gm.w + bt.w;
    if (outf) ((float4*)(outf + (size_t)row * 1024))[tid] = y;
    if (outb) {
        ushort4 ub;
        ub.x = f2bfu(y.x); ub.y = f2bfu(y.y); ub.z = f2bfu(y.z); ub.w = f2bfu(y.w);
        ((ushort4*)outb)[row * 256 + tid] = ub;
    }
}

// ---------------- host ----------------
extern "C" void kernel_launch(void* const* d_in, const int* in_sizes, int n_in,
                              void* d_out, int out_size, void* d_ws, size_t ws_size,
                              hipStream_t stream)
{
    const float* x    = (const float*)d_in[0];
    const unsigned char* kpm = (const unsigned char*)d_in[1];
    const float* Wq = (const float*)d_in[2];
    const float* bq = (const float*)d_in[3];
    const float* Wk = (const float*)d_in[4];
    const float* bk = (const float*)d_in[5];
    const float* Wv = (const float*)d_in[6];
    const float* bv = (const float*)d_in[7];
    const float* Wo = (const float*)d_in[8];
    const float* bo = (const float*)d_in[9];
    const float* W1 = (const float*)d_in[10];
    const float* b1 = (const float*)d_in[11];
    const float* W2 = (const float*)d_in[12];
    const float* b2 = (const float*)d_in[13];
    const float* ln1g = (const float*)d_in[14];
    const float* ln1b = (const float*)d_in[15];
    const float* ln2g = (const float*)d_in[16];
    const float* ln2b = (const float*)d_in[17];
    float* out = (float*)d_out;

    char* ws = (char*)d_ws;
    const size_t SZ_ND2 = (size_t)8192 * 1024 * 2;   // 16.8 MB
    size_t off = 0;
    __hip_bfloat16* xb  = (__hip_bfloat16*)(ws + off); off += SZ_ND2;
    // wq/wk/wv contiguous -> one merged [3072,1024] weight for the QKV GEMM
    __hip_bfloat16* wqb = (__hip_bfloat16*)(ws + off); off += (size_t)1024 * 1024 * 2;
    __hip_bfloat16* wkb = (__hip_bfloat16*)(ws + off); off += (size_t)1024 * 1024 * 2;
    __hip_bfloat16* wvb = (__hip_bfloat16*)(ws + off); off += (size_t)1024 * 1024 * 2;
    __hip_bfloat16* wob = (__hip_bfloat16*)(ws + off); off += (size_t)1024 * 1024 * 2;
    __hip_bfloat16* w1b = (__hip_bfloat16*)(ws + off); off += (size_t)4096 * 1024 * 2;
    __hip_bfloat16* w2b = (__hip_bfloat16*)(ws + off); off += (size_t)4096 * 1024 * 2;
    const size_t qkv0 = off;
    __hip_bfloat16* qbp = (__hip_bfloat16*)(ws + off); off += SZ_ND2;
    __hip_bfloat16* kbp = (__hip_bfloat16*)(ws + off); off += SZ_ND2;
    __hip_bfloat16* vtg = (__hip_bfloat16*)(ws + off); off += SZ_ND2;  // [b][h][dh][s]
    __hip_bfloat16* abp = (__hip_bfloat16*)(ws + off); off += SZ_ND2;
    __hip_bfloat16* hbp = (__hip_bfloat16*)(ws + qkv0);  // aliases q/k/vt/a (dead by then)
    float* y1 = (float*)(ws + off); off += (size_t)8192 * 1024 * 4;
    __hip_bfloat16* x1b = (__hip_bfloat16*)(ws + off); off += SZ_ND2;
    float* y2 = y1;

    // bias concat for QKV GEMM: need contiguous [3072] f32 bias
    float* bqkv = (float*)(ws + off); off += 3072 * 4;

    auto cvt = [&](const float* src, void* dst, int n) {
        cvt_bf16_kernel<<<n / 1024, 256, 0, stream>>>((const float4*)src, (ushort4*)dst, n / 4);
    };
    cvt(x,  xb,  8192 * 1024);
    cvt(Wq, wqb, 1024 * 1024);
    cvt(Wk, wkb, 1024 * 1024);
    cvt(Wv, wvb, 1024 * 1024);
    cvt(Wo, wob, 1024 * 1024);
    cvt(W1, w1b, 4096 * 1024);
    cvt(W2, w2b, 4096 * 1024);
    hipMemcpyAsync(bqkv,        bq, 4096, hipMemcpyDeviceToDevice, stream);
    hipMemcpyAsync(bqkv + 1024, bk, 4096, hipMemcpyDeviceToDevice, stream);
    hipMemcpyAsync(bqkv + 2048, bv, 4096, hipMemcpyDeviceToDevice, stream);

    dim3 blk(256);

    // Q scale folds softmax's log2(e) so attention works in exp2 domain.
    const float qscale = 0.125f * 1.44269504088896f;
    gemm_bt<EPI_QKV><<<dim3(64, 24), blk, 0, stream>>>(
        xb, wqb, bqkv, nullptr, qscale, qbp, kbp, vtg, 8192, 3072, 1024);

    attn_flash2<<<dim3(8, 64), blk, 0, stream>>>(qbp, kbp, vtg, kpm, abp);

    gemm_bt<EPI_RESF32><<<dim3(64, 8), blk, 0, stream>>>(
        abp, wob, bo, x, 1.0f, y1, nullptr, nullptr, 8192, 1024, 1024);
    ln_kernel<<<8192, 256, 0, stream>>>(y1, ln1g, ln1b, nullptr, x1b);

    gemm_bt<EPI_GELU><<<dim3(64, 32), blk, 0, stream>>>(
        x1b, w1b, b1, nullptr, 1.0f, hbp, nullptr, nullptr, 8192, 4096, 1024);
    gemm_bt<EPI_RESBF16><<<dim3(64, 8), blk, 0, stream>>>(
        hbp, w2b, b2, x1b, 1.0f, y2, nullptr, nullptr, 8192, 1024, 4096);
    ln_kernel<<<8192, 256, 0, stream>>>(y2, ln2g, ln2b, out, nullptr);
}